// Round 1
// baseline (1106.515 us; speedup 1.0000x reference)
//
#include <hip/hip_runtime.h>
#include <math.h>

#define BB 2
#define NN 8192
#define CI 64
#define CP 64
#define HH 128
#define WW 128
#define DD 32
#define CF 128

// workspace layout (floats)
static const size_t QOFF  = 0;                       // [B][N][32]
static const size_t XVOFF = QOFF  + (size_t)BB*NN*DD;   // [B][N][64]  (aliased as Y after pass B)
static const size_t RMOFF = XVOFF + (size_t)BB*NN*CP;   // [B][N] rowmax
static const size_t RSOFF = RMOFF + (size_t)BB*NN;      // [B][N] rowsum
static const size_t TOFF  = RSOFF + (size_t)BB*NN;      // [B][N][64]  pts - x_r
static const size_t BNOFF = TOFF  + (size_t)BB*NN*CP;   // [2][64] bn partials

__global__ __launch_bounds__(128) void k_zero(float* bn) {
    bn[threadIdx.x] = 0.f;
}

__device__ __forceinline__ float samp(const float* __restrict__ ib, float yf, float xf) {
    bool v = (xf >= 0.f) && (xf <= (float)(WW - 1)) && (yf >= 0.f) && (yf <= (float)(HH - 1));
    int xi = (int)fminf(fmaxf(xf, 0.f), (float)(WW - 1));
    int yi = (int)fminf(fmaxf(yf, 0.f), (float)(HH - 1));
    return v ? ib[yi * WW + xi] : 0.f;
}

// K1: grid-sample + concat + Q projection + V projection
__global__ __launch_bounds__(256) void k_fuse(
    const float* __restrict__ pts_img, const float* __restrict__ img,
    const float* __restrict__ pfeat, const float* __restrict__ qkw,
    const float* __restrict__ vw, const float* __restrict__ vb,
    float* __restrict__ Q, float* __restrict__ XV)
{
    __shared__ float qk_l[DD * 129];
    __shared__ float vw_l[CP * 65];
    __shared__ float fus[4 * CF];
    int tid = threadIdx.x;
    for (int i = tid; i < DD * CF; i += 256) qk_l[(i >> 7) * 129 + (i & 127)] = qkw[i];
    for (int i = tid; i < CP * CP; i += 256) vw_l[(i >> 6) * 65 + (i & 63)] = vw[i];

    int w = tid >> 6, l = tid & 63;
    int p = blockIdx.x * 4 + w;
    int b = p / NN, n = p % NN;

    float x = pts_img[(size_t)p * 2 + 0], y = pts_img[(size_t)p * 2 + 1];
    float ix = (x + 1.f) * 0.5f * WW - 0.5f;
    float iy = (y + 1.f) * 0.5f * HH - 0.5f;
    float x0 = floorf(ix), y0 = floorf(iy);
    float wx1 = ix - x0, wx0 = 1.f - wx1;
    float wy1 = iy - y0, wy0 = 1.f - wy1;

    int c = l;
    const float* ib = img + ((size_t)b * CI + c) * (HH * WW);
    float v00 = samp(ib, y0, x0);
    float v01 = samp(ib, y0, x0 + 1.f);
    float v10 = samp(ib, y0 + 1.f, x0);
    float v11 = samp(ib, y0 + 1.f, x0 + 1.f);
    float iv = v00 * (wy0 * wx0) + v01 * (wy0 * wx1) + v10 * (wy1 * wx0) + v11 * (wy1 * wx1);
    float pv = pfeat[((size_t)b * CP + c) * NN + n];
    fus[w * CF + c] = iv;
    fus[w * CF + 64 + c] = pv;
    __syncthreads();

    if (l < DD) {
        float acc = 0.f;
        const float* qr = &qk_l[l * 129];
        const float* fp_ = &fus[w * CF];
#pragma unroll
        for (int k = 0; k < CF; ++k) acc += qr[k] * fp_[k];
        Q[((size_t)b * NN + n) * DD + l] = acc;
    }
    {
        float acc = vb[c];
        const float* vr = &vw_l[c * 65];
        const float* fp2 = &fus[w * CF + 64];
#pragma unroll
        for (int k = 0; k < CP; ++k) acc += vr[k] * fp2[k];
        XV[((size_t)b * NN + n) * CP + c] = acc;
    }
}

// K2: per-row online softmax stats over the full N columns
__global__ __launch_bounds__(256) void k_rowstats(
    const float* __restrict__ Q, float* __restrict__ rowmax, float* __restrict__ rowsum)
{
    __shared__ float qc[64 * 36];
    int b = blockIdx.y;
    int rowbase = blockIdx.x * 64;
    int tid = threadIdx.x;
    int g = tid >> 3, t8 = tid & 7;
    int n0 = rowbase + g * 2;

    const float4* Q4 = (const float4*)Q;
    float qr0[32], qr1[32];
    {
        size_t r0 = ((size_t)b * NN + n0) * 8;
#pragma unroll
        for (int i = 0; i < 8; ++i) {
            float4 t = Q4[r0 + i];
            qr0[4 * i] = t.x; qr0[4 * i + 1] = t.y; qr0[4 * i + 2] = t.z; qr0[4 * i + 3] = t.w;
        }
#pragma unroll
        for (int i = 0; i < 8; ++i) {
            float4 t = Q4[r0 + 8 + i];
            qr1[4 * i] = t.x; qr1[4 * i + 1] = t.y; qr1[4 * i + 2] = t.z; qr1[4 * i + 3] = t.w;
        }
    }
    float m0 = -3e38f, s0 = 0.f, m1 = -3e38f, s1 = 0.f;
    int j = tid >> 2, q4 = (tid & 3) * 2;

    for (int ct = 0; ct < NN / 64; ++ct) {
        int colbase = ct * 64;
        __syncthreads();
        {
            size_t src = ((size_t)b * NN + colbase + j) * 8;
            float4 a0 = Q4[src + q4];
            float4 a1 = Q4[src + q4 + 1];
            *(float4*)&qc[j * 36 + q4 * 4] = a0;
            *(float4*)&qc[j * 36 + q4 * 4 + 4] = a1;
        }
        __syncthreads();
#pragma unroll
        for (int k = 0; k < 8; ++k) {
            int jj = t8 + k * 8;
            const float4* qp = (const float4*)&qc[jj * 36];
            float e0 = 0.f, e1 = 0.f;
#pragma unroll
            for (int dd = 0; dd < 8; ++dd) {
                float4 q = qp[dd];
                e0 += qr0[4 * dd] * q.x + qr0[4 * dd + 1] * q.y + qr0[4 * dd + 2] * q.z + qr0[4 * dd + 3] * q.w;
                e1 += qr1[4 * dd] * q.x + qr1[4 * dd + 1] * q.y + qr1[4 * dd + 2] * q.z + qr1[4 * dd + 3] * q.w;
            }
            float M0 = fmaxf(m0, e0); s0 = s0 * __expf(m0 - M0) + __expf(e0 - M0); m0 = M0;
            float M1 = fmaxf(m1, e1); s1 = s1 * __expf(m1 - M1) + __expf(e1 - M1); m1 = M1;
        }
    }
#pragma unroll
    for (int off = 1; off < 8; off <<= 1) {
        float mo = __shfl_xor(m0, off); float so = __shfl_xor(s0, off);
        float M = fmaxf(m0, mo); s0 = s0 * __expf(m0 - M) + so * __expf(mo - M); m0 = M;
        mo = __shfl_xor(m1, off); so = __shfl_xor(s1, off);
        M = fmaxf(m1, mo); s1 = s1 * __expf(m1 - M) + so * __expf(mo - M); m1 = M;
    }
    if (t8 == 0) {
        rowmax[(size_t)b * NN + n0] = m0; rowsum[(size_t)b * NN + n0] = s0;
        rowmax[(size_t)b * NN + n0 + 1] = m1; rowsum[(size_t)b * NN + n0 + 1] = s1;
    }
}

// K3: pass B — P tile + colsum + x_v·P accumulation, write T = pts - x_r
__global__ __launch_bounds__(256) void k_attn(
    const float* __restrict__ Q, const float* __restrict__ XV,
    const float* __restrict__ rowmax, const float* __restrict__ rowsum,
    const float* __restrict__ pfeat, float* __restrict__ T)
{
    __shared__ float qn[64 * 36];
    __shared__ float xvl[64 * 68];
    __shared__ float pl[64 * 64];
    __shared__ float rm[64], irs[64];
    __shared__ float cred[4 * 64];

    int b = blockIdx.y;
    int colbase = blockIdx.x * 64;
    int tid = threadIdx.x;
    int wv = tid >> 6;
    int ml = tid & 63;
    int c8 = ml & 7, m8 = ml >> 3;

    const float4* Q4 = (const float4*)Q;
    float qm[32];
    {
        size_t rq = ((size_t)b * NN + colbase + ml) * 8;
#pragma unroll
        for (int i = 0; i < 8; ++i) {
            float4 t = Q4[rq + i];
            qm[4 * i] = t.x; qm[4 * i + 1] = t.y; qm[4 * i + 2] = t.z; qm[4 * i + 3] = t.w;
        }
    }
    float acc[8][8];
#pragma unroll
    for (int i = 0; i < 8; ++i)
#pragma unroll
        for (int jj = 0; jj < 8; ++jj) acc[i][jj] = 0.f;
    float csum = 0.f;

    int j = tid >> 2, q4 = (tid & 3) * 2;
    int xj = tid >> 2, xf = (tid & 3) * 4;
    const float4* XV4 = (const float4*)XV;

    for (int nt = 0; nt < NN / 64; ++nt) {
        int nb = nt * 64;
        __syncthreads();
        {
            size_t src = ((size_t)b * NN + nb + j) * 8;
            float4 a0 = Q4[src + q4];
            float4 a1 = Q4[src + q4 + 1];
            *(float4*)&qn[j * 36 + q4 * 4] = a0;
            *(float4*)&qn[j * 36 + q4 * 4 + 4] = a1;
        }
        if (tid < 64) {
            rm[tid] = rowmax[(size_t)b * NN + nb + tid];
            irs[tid] = 1.f / rowsum[(size_t)b * NN + nb + tid];
        }
        {
            size_t src = ((size_t)b * NN + nb + xj) * 16;
#pragma unroll
            for (int i = 0; i < 4; ++i) {
                float4 t = XV4[src + xf + i];
                *(float4*)&xvl[xj * 68 + (xf + i) * 4] = t;
            }
        }
        __syncthreads();
        // phase 1: P tile (each wave owns 16 rows)
#pragma unroll
        for (int t = 0; t < 16; ++t) {
            int n = wv * 16 + t;
            const float4* qp = (const float4*)&qn[n * 36];
            float e = 0.f;
#pragma unroll
            for (int dd = 0; dd < 8; ++dd) {
                float4 q = qp[dd];
                e += qm[4 * dd] * q.x + qm[4 * dd + 1] * q.y + qm[4 * dd + 2] * q.z + qm[4 * dd + 3] * q.w;
            }
            float pp = __expf(e - rm[n]) * irs[n];
            pl[n * 64 + ml] = pp;
            csum += pp;
        }
        __syncthreads();
        // phase 2: acc[c8*8+i][m8*8+jj] += xv * P (each wave its 16 rows)
#pragma unroll
        for (int t = 0; t < 16; ++t) {
            int n = wv * 16 + t;
            const float4* pp4 = (const float4*)&pl[n * 64 + m8 * 8];
            float4 pA = pp4[0], pB = pp4[1];
            const float4* xp4 = (const float4*)&xvl[n * 68 + c8 * 8];
            float4 xA = xp4[0], xB = xp4[1];
            float pv[8] = {pA.x, pA.y, pA.z, pA.w, pB.x, pB.y, pB.z, pB.w};
            float xr[8] = {xA.x, xA.y, xA.z, xA.w, xB.x, xB.y, xB.z, xB.w};
#pragma unroll
            for (int i = 0; i < 8; ++i)
#pragma unroll
                for (int jj = 0; jj < 8; ++jj) acc[i][jj] += xr[i] * pv[jj];
        }
    }
    __syncthreads();
    // reduce acc across the 4 waves into pl[c][m]
    for (int k = 0; k < 4; ++k) {
        if (wv == k) {
#pragma unroll
            for (int i = 0; i < 8; ++i)
#pragma unroll
                for (int jj = 0; jj < 8; ++jj) {
                    int cC = c8 * 8 + i, mC = m8 * 8 + jj;
                    if (k == 0) pl[cC * 64 + mC] = acc[i][jj];
                    else pl[cC * 64 + mC] += acc[i][jj];
                }
        }
        __syncthreads();
    }
    cred[wv * 64 + ml] = csum;
    __syncthreads();

    float tot = cred[ml] + cred[64 + ml] + cred[128 + ml] + cred[192 + ml];
    float inv = 1.f / (1e-9f + tot);
    int m = colbase + ml;
#pragma unroll
    for (int i = 0; i < 4; ++i) {
        int c0 = wv * 16 + i * 4;
        float4 o;
        o.x = pfeat[((size_t)b * CP + c0 + 0) * NN + m] - pl[(c0 + 0) * 64 + ml] * inv;
        o.y = pfeat[((size_t)b * CP + c0 + 1) * NN + m] - pl[(c0 + 1) * 64 + ml] * inv;
        o.z = pfeat[((size_t)b * CP + c0 + 2) * NN + m] - pl[(c0 + 2) * 64 + ml] * inv;
        o.w = pfeat[((size_t)b * CP + c0 + 3) * NN + m] - pl[(c0 + 3) * 64 + ml] * inv;
        *(float4*)&T[((size_t)b * NN + m) * CP + c0] = o;
    }
}

// K4: y = t_w @ T + t_b, write Y, accumulate BN partial sums
__global__ __launch_bounds__(256) void k_trans(
    const float* __restrict__ T, const float* __restrict__ tw, const float* __restrict__ tb,
    float* __restrict__ Y, float* __restrict__ bnred)
{
    __shared__ float twl[CP * 65];
    __shared__ float Tl[4][64];
    __shared__ float red[4 * 64];
    int tid = threadIdx.x;
    for (int i = tid; i < CP * CP; i += 256) twl[(i >> 6) * 65 + (i & 63)] = tw[i];
    int w = tid >> 6, l = tid & 63;
    float ys = 0.f, yq = 0.f;
    float tbl = tb[l];
    __syncthreads();
    for (int it = 0; it < 16; ++it) {
        int gp = blockIdx.x * 64 + it * 4 + w;
        __syncthreads();
        Tl[w][l] = T[(size_t)gp * CP + l];
        __syncthreads();
        float acc = tbl;
        const float* tr = &twl[l * 65];
#pragma unroll
        for (int k2 = 0; k2 < CP; ++k2) acc += tr[k2] * Tl[w][k2];
        Y[(size_t)gp * CP + l] = acc;
        ys += acc; yq += acc * acc;
    }
    red[w * 64 + l] = ys;
    __syncthreads();
    if (w == 0) {
        float t = red[l] + red[64 + l] + red[128 + l] + red[192 + l];
        atomicAdd(&bnred[l], t);
    }
    __syncthreads();
    red[w * 64 + l] = yq;
    __syncthreads();
    if (w == 0) {
        float t = red[l] + red[64 + l] + red[128 + l] + red[192 + l];
        atomicAdd(&bnred[64 + l], t);
    }
}

// K5: BN finalize + ReLU + residual
__global__ __launch_bounds__(256) void k_final(
    const float* __restrict__ Y, const float* __restrict__ pfeat,
    const float* __restrict__ gamma, const float* __restrict__ beta,
    const float* __restrict__ bnred, float* __restrict__ out)
{
    int idx = blockIdx.x * 256 + threadIdx.x; // over B*CP*N
    int n = idx % NN;
    int bo = idx / NN;
    int o = bo % CP;
    int b = bo / CP;
    const float invcnt = 1.f / (float)(BB * NN);
    float mean = bnred[o] * invcnt;
    float var = bnred[64 + o] * invcnt - mean * mean;
    float y = Y[((size_t)b * NN + n) * CP + o];
    float z = gamma[o] * (y - mean) * rsqrtf(var + 1e-5f) + beta[o];
    z = fmaxf(z, 0.f);
    out[idx] = pfeat[idx] + z;
}

extern "C" void kernel_launch(void* const* d_in, const int* in_sizes, int n_in,
                              void* d_out, int out_size, void* d_ws, size_t ws_size,
                              hipStream_t stream) {
    const float* pts_img = (const float*)d_in[0];
    const float* img     = (const float*)d_in[1];
    const float* pfeat   = (const float*)d_in[2];
    const float* qkw     = (const float*)d_in[3];
    const float* vw      = (const float*)d_in[4];
    const float* vb      = (const float*)d_in[5];
    const float* tw      = (const float*)d_in[6];
    const float* tb      = (const float*)d_in[7];
    const float* gamma   = (const float*)d_in[8];
    const float* beta    = (const float*)d_in[9];

    float* ws = (float*)d_ws;
    float* Q      = ws + QOFF;
    float* XV     = ws + XVOFF;
    float* rowmax = ws + RMOFF;
    float* rowsum = ws + RSOFF;
    float* T      = ws + TOFF;
    float* Y      = XV;          // alias: XV dead after k_attn
    float* bn     = ws + BNOFF;

    k_zero<<<1, 128, 0, stream>>>(bn);
    k_fuse<<<(BB * NN) / 4, 256, 0, stream>>>(pts_img, img, pfeat, qkw, vw, vb, Q, XV);
    k_rowstats<<<dim3(NN / 64, BB), 256, 0, stream>>>(Q, rowmax, rowsum);
    k_attn<<<dim3(NN / 64, BB), 256, 0, stream>>>(Q, XV, rowmax, rowsum, pfeat, T);
    k_trans<<<(BB * NN) / 64, 256, 0, stream>>>(T, tw, tb, Y, bn);
    k_final<<<(BB * CP * NN) / 256, 256, 0, stream>>>(Y, pfeat, gamma, beta, bn, (float*)d_out);
}

// Round 2
// 276.256 us; speedup vs baseline: 4.0054x; 4.0054x over previous
//
#include <hip/hip_runtime.h>
#include <math.h>

#define BB 2
#define NN 8192
#define CI 64
#define CP 64
#define HH 128
#define WW 128
#define DD 32
#define CF 128

typedef __bf16 bf16_t;
typedef __bf16 bf16x8 __attribute__((ext_vector_type(8)));
typedef __bf16 bf16x4 __attribute__((ext_vector_type(4)));
typedef float f32x4 __attribute__((ext_vector_type(4)));

#define SQ_L2E 1.2011224087864498f   /* sqrt(log2(e)): scales E by log2(e) */

__device__ __forceinline__ float fexp2(float x) { return __builtin_amdgcn_exp2f(x); }

__global__ __launch_bounds__(128) void k_zero(float* bn) {
    bn[threadIdx.x] = 0.f;
}

__device__ __forceinline__ float samp(const float* __restrict__ ib, float yf, float xf) {
    bool v = (xf >= 0.f) && (xf <= (float)(WW - 1)) && (yf >= 0.f) && (yf <= (float)(HH - 1));
    int xi = (int)fminf(fmaxf(xf, 0.f), (float)(WW - 1));
    int yi = (int)fminf(fmaxf(yf, 0.f), (float)(HH - 1));
    return v ? ib[yi * WW + xi] : 0.f;
}

// K1: grid-sample + concat + Q projection (scaled bf16) + V projection (bf16, c-major)
__global__ __launch_bounds__(256) void k_fuse(
    const float* __restrict__ pts_img, const float* __restrict__ img,
    const float* __restrict__ pfeat, const float* __restrict__ qkw,
    const float* __restrict__ vw, const float* __restrict__ vb,
    bf16_t* __restrict__ Qb, bf16_t* __restrict__ XVb)
{
    __shared__ float qk_l[DD * 129];
    __shared__ float vw_l[CP * 65];
    __shared__ float fus[4 * CF];
    int tid = threadIdx.x;
    for (int i = tid; i < DD * CF; i += 256) qk_l[(i >> 7) * 129 + (i & 127)] = qkw[i];
    for (int i = tid; i < CP * CP; i += 256) vw_l[(i >> 6) * 65 + (i & 63)] = vw[i];

    int w = tid >> 6, l = tid & 63;
    int p = blockIdx.x * 4 + w;
    int b = p / NN, n = p % NN;

    float x = pts_img[(size_t)p * 2 + 0], y = pts_img[(size_t)p * 2 + 1];
    float ix = (x + 1.f) * 0.5f * WW - 0.5f;
    float iy = (y + 1.f) * 0.5f * HH - 0.5f;
    float x0 = floorf(ix), y0 = floorf(iy);
    float wx1 = ix - x0, wx0 = 1.f - wx1;
    float wy1 = iy - y0, wy0 = 1.f - wy1;

    int c = l;
    const float* ib = img + ((size_t)b * CI + c) * (HH * WW);
    float v00 = samp(ib, y0, x0);
    float v01 = samp(ib, y0, x0 + 1.f);
    float v10 = samp(ib, y0 + 1.f, x0);
    float v11 = samp(ib, y0 + 1.f, x0 + 1.f);
    float iv = v00 * (wy0 * wx0) + v01 * (wy0 * wx1) + v10 * (wy1 * wx0) + v11 * (wy1 * wx1);
    float pv = pfeat[((size_t)b * CP + c) * NN + n];
    fus[w * CF + c] = iv;
    fus[w * CF + 64 + c] = pv;
    __syncthreads();

    if (l < DD) {
        float acc = 0.f;
        const float* qr = &qk_l[l * 129];
        const float* fp_ = &fus[w * CF];
#pragma unroll
        for (int k = 0; k < CF; ++k) acc += qr[k] * fp_[k];
        Qb[((size_t)b * NN + n) * DD + l] = (bf16_t)(acc * SQ_L2E);
    }
    {
        float acc = vb[c];
        const float* vr = &vw_l[c * 65];
        const float* fp2 = &fus[w * CF + 64];
#pragma unroll
        for (int k = 0; k < CP; ++k) acc += vr[k] * fp2[k];
        XVb[((size_t)b * CP + c) * NN + n] = (bf16_t)acc;
    }
}

// K2: per-row softmax stats via MFMA (exp2 domain; Q pre-scaled by sqrt(log2 e))
__global__ __launch_bounds__(256) void k_rowstats(
    const bf16_t* __restrict__ Qb, float* __restrict__ rm2, float* __restrict__ irs)
{
    int b = blockIdx.y;
    int n0 = blockIdx.x * 64;
    int tid = threadIdx.x;
    int wv = tid >> 6, l = tid & 63;
    int g = l >> 4, c16 = l & 15;
    const bf16x8* Qv = (const bf16x8*)(Qb + (size_t)b * NN * DD);
    bf16x8 afrag = Qv[(size_t)(n0 + wv * 16 + c16) * 4 + g];
    float m2[4] = {-3e38f, -3e38f, -3e38f, -3e38f};
    float ss[4] = {0.f, 0.f, 0.f, 0.f};
    f32x4 z = {0.f, 0.f, 0.f, 0.f};

    bf16x8 nb0 = Qv[(size_t)(c16) * 4 + g];
    bf16x8 nb1 = Qv[(size_t)(16 + c16) * 4 + g];
    bf16x8 nb2 = Qv[(size_t)(32 + c16) * 4 + g];
    bf16x8 nb3 = Qv[(size_t)(48 + c16) * 4 + g];
    for (int mc = 0; mc < NN; mc += 64) {
        bf16x8 b0 = nb0, b1 = nb1, b2 = nb2, b3 = nb3;
        int mn = mc + 64;
        if (mn < NN) {
            nb0 = Qv[(size_t)(mn + c16) * 4 + g];
            nb1 = Qv[(size_t)(mn + 16 + c16) * 4 + g];
            nb2 = Qv[(size_t)(mn + 32 + c16) * 4 + g];
            nb3 = Qv[(size_t)(mn + 48 + c16) * 4 + g];
        }
        f32x4 e0 = __builtin_amdgcn_mfma_f32_16x16x32_bf16(afrag, b0, z, 0, 0, 0);
        f32x4 e1 = __builtin_amdgcn_mfma_f32_16x16x32_bf16(afrag, b1, z, 0, 0, 0);
        f32x4 e2 = __builtin_amdgcn_mfma_f32_16x16x32_bf16(afrag, b2, z, 0, 0, 0);
        f32x4 e3 = __builtin_amdgcn_mfma_f32_16x16x32_bf16(afrag, b3, z, 0, 0, 0);
#pragma unroll
        for (int r = 0; r < 4; ++r) {
            float M = fmaxf(fmaxf(fmaxf(e0[r], e1[r]), fmaxf(e2[r], e3[r])), m2[r]);
            ss[r] = ss[r] * fexp2(m2[r] - M)
                  + fexp2(e0[r] - M) + fexp2(e1[r] - M) + fexp2(e2[r] - M) + fexp2(e3[r] - M);
            m2[r] = M;
        }
    }
#pragma unroll
    for (int off = 1; off < 16; off <<= 1) {
#pragma unroll
        for (int r = 0; r < 4; ++r) {
            float Mo = __shfl_xor(m2[r], off);
            float so = __shfl_xor(ss[r], off);
            float M = fmaxf(m2[r], Mo);
            ss[r] = ss[r] * fexp2(m2[r] - M) + so * fexp2(Mo - M);
            m2[r] = M;
        }
    }
    if (c16 == 0) {
#pragma unroll
        for (int r = 0; r < 4; ++r) {
            int n = n0 + wv * 16 + 4 * g + r;
            rm2[(size_t)b * NN + n] = m2[r];
            irs[(size_t)b * NN + n] = 1.f / ss[r];
        }
    }
}

// K3: pass B — MFMA energy + P + colsum + MFMA PV, write T = pts - x_r (point-major)
__global__ __launch_bounds__(512) void k_attn(
    const bf16_t* __restrict__ Qb, const bf16_t* __restrict__ XVb,
    const float* __restrict__ rm2, const float* __restrict__ irs,
    const float* __restrict__ pfeat, float* __restrict__ T)
{
    __shared__ __align__(16) bf16_t xvs[64 * 72];
    __shared__ __align__(16) float rmL[64];
    __shared__ __align__(16) float irsL[64];
    __shared__ __align__(16) float accL[64 * 66];
    __shared__ float cred[8 * 16];
    __shared__ float invL[64];

    int b = blockIdx.y;
    int m0 = blockIdx.x * 64;
    int tid = threadIdx.x;
    int wv = tid >> 6, l = tid & 63;
    int g = l >> 4, c16 = l & 15;
    int msub = wv & 3, par = wv >> 2;

    const bf16x8* Qv = (const bf16x8*)(Qb + (size_t)b * NN * DD);
    bf16x8 bq = Qv[(size_t)(m0 + msub * 16 + c16) * 4 + g];
    f32x4 z = {0.f, 0.f, 0.f, 0.f};
    f32x4 acc[4];
#pragma unroll
    for (int ci = 0; ci < 4; ++ci) acc[ci] = z;
    float csum = 0.f;

    const bf16_t* XVbase = XVb + (size_t)b * CP * NN;
    const float* rmb = rm2 + (size_t)b * NN;
    const float* irb = irs + (size_t)b * NN;

    int sc = tid >> 3, sseg = tid & 7;
    const int nloc = par * 32 + 4 * g;

    // prefetch first A-frags
    bf16x8 a0 = Qv[(size_t)(par * 32 + c16) * 4 + g];
    bf16x8 a1 = Qv[(size_t)(par * 32 + 16 + c16) * 4 + g];

    for (int nc = 0; nc < NN; nc += 64) {
        __syncthreads();
        {
            const uint4* src = (const uint4*)(XVbase + (size_t)sc * NN + nc);
            *(uint4*)&xvs[sc * 72 + sseg * 8] = src[sseg];
            if (tid < 64) { rmL[tid] = rmb[nc + tid]; irsL[tid] = irb[nc + tid]; }
        }
        __syncthreads();

        bf16x8 ca0 = a0, ca1 = a1;
        int nn2 = nc + 64;
        if (nn2 < NN) {
            a0 = Qv[(size_t)(nn2 + par * 32 + c16) * 4 + g];
            a1 = Qv[(size_t)(nn2 + par * 32 + 16 + c16) * 4 + g];
        }
        f32x4 E0 = __builtin_amdgcn_mfma_f32_16x16x32_bf16(ca0, bq, z, 0, 0, 0);
        f32x4 E1 = __builtin_amdgcn_mfma_f32_16x16x32_bf16(ca1, bq, z, 0, 0, 0);

        f32x4 rv0 = *(const f32x4*)&rmL[nloc];
        f32x4 iv0 = *(const f32x4*)&irsL[nloc];
        f32x4 rv1 = *(const f32x4*)&rmL[nloc + 16];
        f32x4 iv1 = *(const f32x4*)&irsL[nloc + 16];

        float p0 = fexp2(E0[0] - rv0[0]) * iv0[0];
        float p1 = fexp2(E0[1] - rv0[1]) * iv0[1];
        float p2 = fexp2(E0[2] - rv0[2]) * iv0[2];
        float p3 = fexp2(E0[3] - rv0[3]) * iv0[3];
        float p4 = fexp2(E1[0] - rv1[0]) * iv1[0];
        float p5 = fexp2(E1[1] - rv1[1]) * iv1[1];
        float p6 = fexp2(E1[2] - rv1[2]) * iv1[2];
        float p7 = fexp2(E1[3] - rv1[3]) * iv1[3];
        csum += ((p0 + p1) + (p2 + p3)) + ((p4 + p5) + (p6 + p7));

        bf16x8 bp;
        bp[0] = (bf16_t)p0; bp[1] = (bf16_t)p1; bp[2] = (bf16_t)p2; bp[3] = (bf16_t)p3;
        bp[4] = (bf16_t)p4; bp[5] = (bf16_t)p5; bp[6] = (bf16_t)p6; bp[7] = (bf16_t)p7;

        int xoff = par * 32 + 4 * g;
#pragma unroll
        for (int ci = 0; ci < 4; ++ci) {
            int c = ci * 16 + c16;
            bf16x4 lo = *(const bf16x4*)&xvs[c * 72 + xoff];
            bf16x4 hi = *(const bf16x4*)&xvs[c * 72 + xoff + 16];
            bf16x8 av;
            av[0] = lo[0]; av[1] = lo[1]; av[2] = lo[2]; av[3] = lo[3];
            av[4] = hi[0]; av[5] = hi[1]; av[6] = hi[2]; av[7] = hi[3];
            acc[ci] = __builtin_amdgcn_mfma_f32_16x16x32_bf16(av, bp, acc[ci], 0, 0, 0);
        }
    }

    // ---- epilogue ----
    csum += __shfl_xor(csum, 16);
    csum += __shfl_xor(csum, 32);
    if (l < 16) cred[wv * 16 + l] = csum;
    __syncthreads();
    if (tid < 64) {
        float tot = cred[(tid >> 4) * 16 + (tid & 15)] + cred[((tid >> 4) + 4) * 16 + (tid & 15)];
        invL[tid] = 1.f / (1e-9f + tot);
    }
    if (par == 0) {
#pragma unroll
        for (int ci = 0; ci < 4; ++ci)
#pragma unroll
            for (int r = 0; r < 4; ++r)
                accL[(ci * 16 + 4 * g + r) * 66 + msub * 16 + c16] = acc[ci][r];
    }
    __syncthreads();
    if (par == 1) {
#pragma unroll
        for (int ci = 0; ci < 4; ++ci)
#pragma unroll
            for (int r = 0; r < 4; ++r)
                accL[(ci * 16 + 4 * g + r) * 66 + msub * 16 + c16] += acc[ci][r];
    }
    __syncthreads();
    {
        int c = tid >> 3, m8 = (tid & 7) * 8;
        const float* pf = pfeat + ((size_t)b * CP + c) * NN + m0 + m8;
        float4 pa = *(const float4*)pf;
        float4 pb = *(const float4*)(pf + 4);
        float* ar = &accL[c * 66 + m8];
        ar[0] = pa.x - ar[0] * invL[m8 + 0];
        ar[1] = pa.y - ar[1] * invL[m8 + 1];
        ar[2] = pa.z - ar[2] * invL[m8 + 2];
        ar[3] = pa.w - ar[3] * invL[m8 + 3];
        ar[4] = pb.x - ar[4] * invL[m8 + 4];
        ar[5] = pb.y - ar[5] * invL[m8 + 5];
        ar[6] = pb.z - ar[6] * invL[m8 + 6];
        ar[7] = pb.w - ar[7] * invL[m8 + 7];
    }
    __syncthreads();
    {
        int m = tid >> 3, c8 = (tid & 7) * 8;
        float4 o0, o1;
        o0.x = accL[(c8 + 0) * 66 + m];
        o0.y = accL[(c8 + 1) * 66 + m];
        o0.z = accL[(c8 + 2) * 66 + m];
        o0.w = accL[(c8 + 3) * 66 + m];
        o1.x = accL[(c8 + 4) * 66 + m];
        o1.y = accL[(c8 + 5) * 66 + m];
        o1.z = accL[(c8 + 6) * 66 + m];
        o1.w = accL[(c8 + 7) * 66 + m];
        float* dst = T + ((size_t)b * NN + m0 + m) * CP + c8;
        *(float4*)dst = o0;
        *(float4*)(dst + 4) = o1;
    }
}

// K4: y = t_w @ T + t_b, write Y, accumulate BN partial sums
__global__ __launch_bounds__(256) void k_trans(
    const float* __restrict__ T, const float* __restrict__ tw, const float* __restrict__ tb,
    float* __restrict__ Y, float* __restrict__ bnred)
{
    __shared__ float twl[CP * 65];
    __shared__ float Tl[4][64];
    __shared__ float red[4 * 64];
    int tid = threadIdx.x;
    for (int i = tid; i < CP * CP; i += 256) twl[(i >> 6) * 65 + (i & 63)] = tw[i];
    int w = tid >> 6, l = tid & 63;
    float ys = 0.f, yq = 0.f;
    float tbl = tb[l];
    __syncthreads();
    for (int it = 0; it < 16; ++it) {
        int gp = blockIdx.x * 64 + it * 4 + w;
        __syncthreads();
        Tl[w][l] = T[(size_t)gp * CP + l];
        __syncthreads();
        float acc = tbl;
        const float* tr = &twl[l * 65];
#pragma unroll
        for (int k2 = 0; k2 < CP; ++k2) acc += tr[k2] * Tl[w][k2];
        Y[(size_t)gp * CP + l] = acc;
        ys += acc; yq += acc * acc;
    }
    red[w * 64 + l] = ys;
    __syncthreads();
    if (w == 0) {
        float t = red[l] + red[64 + l] + red[128 + l] + red[192 + l];
        atomicAdd(&bnred[l], t);
    }
    __syncthreads();
    red[w * 64 + l] = yq;
    __syncthreads();
    if (w == 0) {
        float t = red[l] + red[64 + l] + red[128 + l] + red[192 + l];
        atomicAdd(&bnred[64 + l], t);
    }
}

// K5: BN finalize + ReLU + residual
__global__ __launch_bounds__(256) void k_final(
    const float* __restrict__ Y, const float* __restrict__ pfeat,
    const float* __restrict__ gamma, const float* __restrict__ beta,
    const float* __restrict__ bnred, float* __restrict__ out)
{
    int idx = blockIdx.x * 256 + threadIdx.x; // over B*CP*N
    int n = idx % NN;
    int bo = idx / NN;
    int o = bo % CP;
    int b = bo / CP;
    const float invcnt = 1.f / (float)(BB * NN);
    float mean = bnred[o] * invcnt;
    float var = bnred[64 + o] * invcnt - mean * mean;
    float y = Y[((size_t)b * NN + n) * CP + o];
    float zz = gamma[o] * (y - mean) * rsqrtf(var + 1e-5f) + beta[o];
    zz = fmaxf(zz, 0.f);
    out[idx] = pfeat[idx] + zz;
}

extern "C" void kernel_launch(void* const* d_in, const int* in_sizes, int n_in,
                              void* d_out, int out_size, void* d_ws, size_t ws_size,
                              hipStream_t stream) {
    const float* pts_img = (const float*)d_in[0];
    const float* img     = (const float*)d_in[1];
    const float* pfeat   = (const float*)d_in[2];
    const float* qkw     = (const float*)d_in[3];
    const float* vw      = (const float*)d_in[4];
    const float* vb      = (const float*)d_in[5];
    const float* tw      = (const float*)d_in[6];
    const float* tb      = (const float*)d_in[7];
    const float* gamma   = (const float*)d_in[8];
    const float* beta    = (const float*)d_in[9];

    // byte-offset workspace layout (total ~8.4 MB)
    char* base = (char*)d_ws;
    float*  T   = (float*)(base);                  // 4,194,304 B  [B][N][64] f32
    float*  bn  = (float*)(base + 4194304);        // 512 B
    char*   S   = base + 4194816;
    bf16_t* Qb  = (bf16_t*)(S);                    // 1,048,576 B  [B][N][32] bf16 (scaled)
    bf16_t* XVb = (bf16_t*)(S + 1048576);          // 2,097,152 B  [B][64][N] bf16
    float*  rm2 = (float*)(S + 3145728);           // 65,536 B
    float*  irs = (float*)(S + 3211264);           // 65,536 B
    float*  Y   = (float*)(S);                     // alias (Qb..irs dead after k_attn)

    k_zero<<<1, 128, 0, stream>>>(bn);
    k_fuse<<<(BB * NN) / 4, 256, 0, stream>>>(pts_img, img, pfeat, qkw, vw, vb, Qb, XVb);
    k_rowstats<<<dim3(NN / 64, BB), 256, 0, stream>>>(Qb, rm2, irs);
    k_attn<<<dim3(NN / 64, BB), 512, 0, stream>>>(Qb, XVb, rm2, irs, pfeat, T);
    k_trans<<<(BB * NN) / 64, 256, 0, stream>>>(T, tw, tb, Y, bn);
    k_final<<<(BB * CP * NN) / 256, 256, 0, stream>>>(Y, pfeat, gamma, beta, bn, (float*)d_out);
}

// Round 3
// 199.413 us; speedup vs baseline: 5.5489x; 1.3853x over previous
//
#include <hip/hip_runtime.h>
#include <math.h>

#define BB 2
#define NN 8192
#define CI 64
#define CP 64
#define HH 128
#define WW 128
#define DD 32
#define CF 128
#define SPLITM 4

typedef __bf16 bf16_t;
typedef __bf16 bf16x8 __attribute__((ext_vector_type(8)));
typedef __bf16 bf16x4 __attribute__((ext_vector_type(4)));
typedef float f32x4 __attribute__((ext_vector_type(4)));

#define SQ_L2E 1.2011224087864498f   /* sqrt(log2(e)) */

__device__ __forceinline__ float fexp2(float x) { return __builtin_amdgcn_exp2f(x); }

__device__ __forceinline__ bf16x8 pack8(float a0,float a1,float a2,float a3,
                                        float b0,float b1,float b2,float b3){
    bf16x8 r;
    r[0]=(bf16_t)a0; r[1]=(bf16_t)a1; r[2]=(bf16_t)a2; r[3]=(bf16_t)a3;
    r[4]=(bf16_t)b0; r[5]=(bf16_t)b1; r[6]=(bf16_t)b2; r[7]=(bf16_t)b3;
    return r;
}

__device__ __forceinline__ bf16x8 ld_av(const bf16_t* p){
    bf16x4 lo = *(const bf16x4*)p;
    bf16x4 hi = *(const bf16x4*)(p + 16);
    bf16x8 r;
    r[0]=lo[0];r[1]=lo[1];r[2]=lo[2];r[3]=lo[3];
    r[4]=hi[0];r[5]=hi[1];r[6]=hi[2];r[7]=hi[3];
    return r;
}

__device__ __forceinline__ float samp(const float* __restrict__ ib, float yf, float xf) {
    bool v = (xf >= 0.f) && (xf <= (float)(WW - 1)) && (yf >= 0.f) && (yf <= (float)(HH - 1));
    int xi = (int)fminf(fmaxf(xf, 0.f), (float)(WW - 1));
    int yi = (int)fminf(fmaxf(yf, 0.f), (float)(HH - 1));
    return v ? ib[yi * WW + xi] : 0.f;
}

// prep: convert t_w to bf16
__global__ __launch_bounds__(256) void k_prep(const float* __restrict__ tw, bf16_t* __restrict__ twb) {
    int i = blockIdx.x * 256 + threadIdx.x;
    if (i < CP * CP) twb[i] = (bf16_t)tw[i];
}

// K1: grid-sample + concat + Q projection (scaled bf16) + V projection (bf16, c-major)
__global__ __launch_bounds__(256) void k_fuse(
    const float* __restrict__ pts_img, const float* __restrict__ img,
    const float* __restrict__ pfeat, const float* __restrict__ qkw,
    const float* __restrict__ vw, const float* __restrict__ vb,
    bf16_t* __restrict__ Qb, bf16_t* __restrict__ XVb)
{
    __shared__ float qk_l[DD * 129];
    __shared__ float vw_l[CP * 65];
    __shared__ float fus[4 * CF];
    int tid = threadIdx.x;
    for (int i = tid; i < DD * CF; i += 256) qk_l[(i >> 7) * 129 + (i & 127)] = qkw[i];
    for (int i = tid; i < CP * CP; i += 256) vw_l[(i >> 6) * 65 + (i & 63)] = vw[i];

    int w = tid >> 6, l = tid & 63;
    int p = blockIdx.x * 4 + w;
    int b = p / NN, n = p % NN;

    float x = pts_img[(size_t)p * 2 + 0], y = pts_img[(size_t)p * 2 + 1];
    float ix = (x + 1.f) * 0.5f * WW - 0.5f;
    float iy = (y + 1.f) * 0.5f * HH - 0.5f;
    float x0 = floorf(ix), y0 = floorf(iy);
    float wx1 = ix - x0, wx0 = 1.f - wx1;
    float wy1 = iy - y0, wy0 = 1.f - wy1;

    int c = l;
    const float* ib = img + ((size_t)b * CI + c) * (HH * WW);
    float v00 = samp(ib, y0, x0);
    float v01 = samp(ib, y0, x0 + 1.f);
    float v10 = samp(ib, y0 + 1.f, x0);
    float v11 = samp(ib, y0 + 1.f, x0 + 1.f);
    float iv = v00 * (wy0 * wx0) + v01 * (wy0 * wx1) + v10 * (wy1 * wx0) + v11 * (wy1 * wx1);
    float pv = pfeat[((size_t)b * CP + c) * NN + n];
    fus[w * CF + c] = iv;
    fus[w * CF + 64 + c] = pv;
    __syncthreads();

    // Q dot: all 64 lanes (qo = l&31, k-half = l>>5), then pair-reduce
    {
        int qo = l & 31, kh = l >> 5;
        float acc = 0.f;
        const float* qr = &qk_l[qo * 129 + kh * 64];
        const float* fp_ = &fus[w * CF + kh * 64];
#pragma unroll
        for (int k = 0; k < 64; ++k) acc += qr[k] * fp_[k];
        acc += __shfl_xor(acc, 32);
        if (kh == 0) Qb[((size_t)b * NN + n) * DD + qo] = (bf16_t)(acc * SQ_L2E);
    }
    {
        float acc = vb[c];
        const float* vr = &vw_l[c * 65];
        const float* fp2 = &fus[w * CF + 64];
#pragma unroll
        for (int k = 0; k < CP; ++k) acc += vr[k] * fp2[k];
        XVb[((size_t)b * CP + c) * NN + n] = (bf16_t)acc;
    }
}

// K2: rowsum[n] = sum_m exp2(E[n,m]), no max (exp2 domain, huge headroom). m-split + atomics.
__global__ __launch_bounds__(256) void k_rowsum(
    const bf16_t* __restrict__ Qb, float* __restrict__ rowsumG)
{
    int b = blockIdx.z;
    int n0 = blockIdx.x * 64;
    int mchunk = blockIdx.y * (NN / SPLITM);
    int tid = threadIdx.x;
    int wv = tid >> 6, l = tid & 63;
    int g = l >> 4, c16 = l & 15;
    const bf16x8* Qv = (const bf16x8*)(Qb + (size_t)b * NN * DD);
    f32x4 z = {0.f, 0.f, 0.f, 0.f};

    bf16x8 A0 = Qv[(size_t)(n0 +  0 + c16) * 4 + g];
    bf16x8 A1 = Qv[(size_t)(n0 + 16 + c16) * 4 + g];
    bf16x8 A2 = Qv[(size_t)(n0 + 32 + c16) * 4 + g];
    bf16x8 A3 = Qv[(size_t)(n0 + 48 + c16) * 4 + g];

    float rs[4][4];
#pragma unroll
    for (int a = 0; a < 4; ++a)
#pragma unroll
        for (int r = 0; r < 4; ++r) rs[a][r] = 0.f;

    int mbase = mchunk + wv * 64;
    bf16x8 Bn0 = Qv[(size_t)(mbase +  0 + c16) * 4 + g];
    bf16x8 Bn1 = Qv[(size_t)(mbase + 16 + c16) * 4 + g];
    bf16x8 Bn2 = Qv[(size_t)(mbase + 32 + c16) * 4 + g];
    bf16x8 Bn3 = Qv[(size_t)(mbase + 48 + c16) * 4 + g];

    const int NIT = NN / SPLITM / 256;  // 8
    for (int it = 0; it < NIT; ++it) {
        bf16x8 B0 = Bn0, B1 = Bn1, B2 = Bn2, B3 = Bn3;
        int mnext = mbase + 256;
        if (it + 1 < NIT) {
            Bn0 = Qv[(size_t)(mnext +  0 + c16) * 4 + g];
            Bn1 = Qv[(size_t)(mnext + 16 + c16) * 4 + g];
            Bn2 = Qv[(size_t)(mnext + 32 + c16) * 4 + g];
            Bn3 = Qv[(size_t)(mnext + 48 + c16) * 4 + g];
        }
#define ROWSTEP(Aa, a)                                                        \
        {                                                                     \
            f32x4 e0 = __builtin_amdgcn_mfma_f32_16x16x32_bf16(Aa, B0, z, 0, 0, 0); \
            f32x4 e1 = __builtin_amdgcn_mfma_f32_16x16x32_bf16(Aa, B1, z, 0, 0, 0); \
            f32x4 e2 = __builtin_amdgcn_mfma_f32_16x16x32_bf16(Aa, B2, z, 0, 0, 0); \
            f32x4 e3 = __builtin_amdgcn_mfma_f32_16x16x32_bf16(Aa, B3, z, 0, 0, 0); \
            _Pragma("unroll")                                                 \
            for (int r = 0; r < 4; ++r)                                       \
                rs[a][r] += (fexp2(e0[r]) + fexp2(e1[r])) + (fexp2(e2[r]) + fexp2(e3[r])); \
        }
        ROWSTEP(A0, 0) ROWSTEP(A1, 1) ROWSTEP(A2, 2) ROWSTEP(A3, 3)
#undef ROWSTEP
        mbase = mnext;
    }
#pragma unroll
    for (int a = 0; a < 4; ++a)
#pragma unroll
        for (int r = 0; r < 4; ++r) {
            float v = rs[a][r];
            v += __shfl_xor(v, 1);
            v += __shfl_xor(v, 2);
            v += __shfl_xor(v, 4);
            v += __shfl_xor(v, 8);
            if (c16 == 0)
                atomicAdd(&rowsumG[(size_t)b * NN + n0 + 16 * a + 4 * g + r], v);
        }
}

// K3 fused: energy + P + colsum + PV + L1-renorm + (pts - x_r) + t_w conv -> Y + BN partials
__global__ __launch_bounds__(256) void k_attn(
    const bf16_t* __restrict__ Qb, const bf16_t* __restrict__ XVb,
    const float* __restrict__ rowsumG, const float* __restrict__ pfeat,
    const bf16_t* __restrict__ twb, const float* __restrict__ tb,
    float* __restrict__ Y, float* __restrict__ bnred)
{
    __shared__ __align__(16) bf16_t xvs[2][64][136];   // stride 68 dwords -> 2-way max (free)
    __shared__ __align__(16) float irsL[2][128];
    __shared__ float csL[128];
    __shared__ float invc[32];

    int b = blockIdx.y;
    int m0 = blockIdx.x * 32;
    int tid = threadIdx.x;
    int wv = tid >> 6, l = tid & 63;
    int g = l >> 4, c16 = l & 15;

    const bf16x8* Qv = (const bf16x8*)(Qb + (size_t)b * NN * DD);
    const bf16_t* XVbase = XVb + (size_t)b * CP * NN;
    const float* rsb = rowsumG + (size_t)b * NN;

    bf16x8 bq0 = Qv[(size_t)(m0 + c16) * 4 + g];
    bf16x8 bq1 = Qv[(size_t)(m0 + 16 + c16) * 4 + g];

    f32x4 z = {0.f, 0.f, 0.f, 0.f};
    f32x4 acc[4][2];
#pragma unroll
    for (int ci = 0; ci < 4; ++ci) { acc[ci][0] = z; acc[ci][1] = z; }
    float cs0 = 0.f, cs1 = 0.f;

    int sc = tid >> 2, snq = (tid & 3) * 32;
    const bf16_t* srcrow = XVbase + (size_t)sc * NN;

    uint4 st0, st1, st2, st3;
    float irsv = 0.f;
    // load tile 0
    {
        const uint4* s4 = (const uint4*)(srcrow + snq);
        st0 = s4[0]; st1 = s4[1]; st2 = s4[2]; st3 = s4[3];
        if (tid < 128) irsv = 1.0f / rsb[tid];
    }
    // write buf 0
    {
        *(uint4*)&xvs[0][sc][snq +  0] = st0;
        *(uint4*)&xvs[0][sc][snq +  8] = st1;
        *(uint4*)&xvs[0][sc][snq + 16] = st2;
        *(uint4*)&xvs[0][sc][snq + 24] = st3;
        if (tid < 128) irsL[0][tid] = irsv;
    }
    // load tile 1
    {
        const uint4* s4 = (const uint4*)(srcrow + 128 + snq);
        st0 = s4[0]; st1 = s4[1]; st2 = s4[2]; st3 = s4[3];
        if (tid < 128) irsv = 1.0f / rsb[128 + tid];
    }
    // A prefetch tile 0
    bf16x8 a0 = Qv[(size_t)(32 * wv + c16) * 4 + g];
    bf16x8 a1 = Qv[(size_t)(32 * wv + 16 + c16) * 4 + g];
    __syncthreads();

    const int NT = NN / 128;  // 64
    for (int it = 0; it < NT; ++it) {
        int buf = it & 1;
        // write staged tile it+1 into buf^1 (read last at iter it-1, barrier'd)
        {
            *(uint4*)&xvs[buf ^ 1][sc][snq +  0] = st0;
            *(uint4*)&xvs[buf ^ 1][sc][snq +  8] = st1;
            *(uint4*)&xvs[buf ^ 1][sc][snq + 16] = st2;
            *(uint4*)&xvs[buf ^ 1][sc][snq + 24] = st3;
            if (tid < 128) irsL[buf ^ 1][tid] = irsv;
        }
        // issue loads for tile it+2 (clamped; garbage tiles never consumed)
        {
            int nbase2 = it * 128 + 256;
            int nld = (nbase2 < NN) ? nbase2 : it * 128;
            const uint4* s4 = (const uint4*)(srcrow + nld + snq);
            st0 = s4[0]; st1 = s4[1]; st2 = s4[2]; st3 = s4[3];
            if (tid < 128) irsv = 1.0f / rsb[nld + tid];
        }
        // A frags: current + prefetch next
        bf16x8 ca0 = a0, ca1 = a1;
        {
            int nA = ((it + 1 < NT) ? (it + 1) * 128 : 0) + 32 * wv;
            a0 = Qv[(size_t)(nA + c16) * 4 + g];
            a1 = Qv[(size_t)(nA + 16 + c16) * 4 + g];
        }

        f32x4 E00 = __builtin_amdgcn_mfma_f32_16x16x32_bf16(ca0, bq0, z, 0, 0, 0);
        f32x4 E01 = __builtin_amdgcn_mfma_f32_16x16x32_bf16(ca0, bq1, z, 0, 0, 0);
        f32x4 E10 = __builtin_amdgcn_mfma_f32_16x16x32_bf16(ca1, bq0, z, 0, 0, 0);
        f32x4 E11 = __builtin_amdgcn_mfma_f32_16x16x32_bf16(ca1, bq1, z, 0, 0, 0);

        f32x4 iv0 = *(const f32x4*)&irsL[buf][32 * wv + 4 * g];
        f32x4 iv1 = *(const f32x4*)&irsL[buf][32 * wv + 16 + 4 * g];

        float p00[4], p01[4], p10[4], p11[4];
#pragma unroll
        for (int r = 0; r < 4; ++r) {
            p00[r] = fexp2(E00[r]) * iv0[r];
            p01[r] = fexp2(E01[r]) * iv0[r];
            p10[r] = fexp2(E10[r]) * iv1[r];
            p11[r] = fexp2(E11[r]) * iv1[r];
        }
        cs0 += ((p00[0] + p00[1]) + (p00[2] + p00[3])) + ((p10[0] + p10[1]) + (p10[2] + p10[3]));
        cs1 += ((p01[0] + p01[1]) + (p01[2] + p01[3])) + ((p11[0] + p11[1]) + (p11[2] + p11[3]));

        bf16x8 bp0 = pack8(p00[0], p00[1], p00[2], p00[3], p10[0], p10[1], p10[2], p10[3]);
        bf16x8 bp1 = pack8(p01[0], p01[1], p01[2], p01[3], p11[0], p11[1], p11[2], p11[3]);

#pragma unroll
        for (int ci = 0; ci < 4; ++ci) {
            const bf16_t* xr = &xvs[buf][16 * ci + c16][32 * wv + 4 * g];
            bf16x8 av = ld_av(xr);
            acc[ci][0] = __builtin_amdgcn_mfma_f32_16x16x32_bf16(av, bp0, acc[ci][0], 0, 0, 0);
            acc[ci][1] = __builtin_amdgcn_mfma_f32_16x16x32_bf16(av, bp1, acc[ci][1], 0, 0, 0);
        }
        __syncthreads();
    }

    // ---- epilogue ----
    cs0 += __shfl_xor(cs0, 16); cs0 += __shfl_xor(cs0, 32);
    cs1 += __shfl_xor(cs1, 16); cs1 += __shfl_xor(cs1, 32);
    if (l < 16) { csL[wv * 32 + l] = cs0; csL[wv * 32 + 16 + l] = cs1; }
    __syncthreads();
    if (tid < 32) {
        float tot = csL[tid] + csL[32 + tid] + csL[64 + tid] + csL[96 + tid];
        invc[tid] = 1.f / (1e-9f + tot);
    }
    // reduce acc across the 4 waves into accL[c][m] (aliases xvs)
    float* accL = (float*)&xvs[0][0][0];  // [64][34]
    for (int k = 0; k < 4; ++k) {
        if (wv == k) {
#pragma unroll
            for (int ci = 0; ci < 4; ++ci)
#pragma unroll
                for (int j = 0; j < 2; ++j)
#pragma unroll
                    for (int r = 0; r < 4; ++r) {
                        int cc = 16 * ci + 4 * g + r, mm = 16 * j + c16;
                        if (k == 0) accL[cc * 34 + mm] = acc[ci][j][r];
                        else        accL[cc * 34 + mm] += acc[ci][j][r];
                    }
        }
        __syncthreads();
    }
    // T = pfeat - x_r (in accL, f32)
    {
        int mm = tid & 31, cq = tid >> 5;
        float ic = invc[mm];
#pragma unroll
        for (int k = 0; k < 8; ++k) {
            int cc = cq * 8 + k;
            float pf = pfeat[((size_t)b * CP + cc) * NN + m0 + mm];
            accL[cc * 34 + mm] = pf - accL[cc * 34 + mm] * ic;
        }
    }
    __syncthreads();
    // t-conv via MFMA: wave wv owns o-group wv
    {
        const bf16_t* twr = twb + (size_t)(16 * wv + c16) * 64;
        bf16x8 Aw0 = ld_av(twr + 4 * g);
        bf16x8 Aw1 = ld_av(twr + 32 + 4 * g);
        f32x4 y0 = z, y1 = z;
#pragma unroll
        for (int ck = 0; ck < 2; ++ck) {
            bf16x8 B0, B1;
#pragma unroll
            for (int r = 0; r < 4; ++r) {
                int klo = 32 * ck + 4 * g + r, khi = 32 * ck + 16 + 4 * g + r;
                B0[r]     = (bf16_t)accL[klo * 34 + c16];
                B0[4 + r] = (bf16_t)accL[khi * 34 + c16];
                B1[r]     = (bf16_t)accL[klo * 34 + 16 + c16];
                B1[4 + r] = (bf16_t)accL[khi * 34 + 16 + c16];
            }
            bf16x8 Ac = ck ? Aw1 : Aw0;
            y0 = __builtin_amdgcn_mfma_f32_16x16x32_bf16(Ac, B0, y0, 0, 0, 0);
            y1 = __builtin_amdgcn_mfma_f32_16x16x32_bf16(Ac, B1, y1, 0, 0, 0);
        }
        f32x4 tbv = *(const f32x4*)&tb[16 * wv + 4 * g];
#pragma unroll
        for (int r = 0; r < 4; ++r) {
            int o = 16 * wv + 4 * g + r;
            float ya = y0[r] + tbv[r];
            float yb = y1[r] + tbv[r];
            Y[((size_t)b * CP + o) * NN + m0 + c16] = ya;
            Y[((size_t)b * CP + o) * NN + m0 + 16 + c16] = yb;
            float sv = ya + yb, sq = ya * ya + yb * yb;
            sv += __shfl_xor(sv, 1); sq += __shfl_xor(sq, 1);
            sv += __shfl_xor(sv, 2); sq += __shfl_xor(sq, 2);
            sv += __shfl_xor(sv, 4); sq += __shfl_xor(sq, 4);
            sv += __shfl_xor(sv, 8); sq += __shfl_xor(sq, 8);
            if (c16 == 0) {
                atomicAdd(&bnred[o], sv);
                atomicAdd(&bnred[64 + o], sq);
            }
        }
    }
}

// K5: BN finalize + ReLU + residual (Y is c-major, same flat layout as out)
__global__ __launch_bounds__(256) void k_final(
    const float* __restrict__ Y, const float* __restrict__ pfeat,
    const float* __restrict__ gamma, const float* __restrict__ beta,
    const float* __restrict__ bnred, float* __restrict__ out)
{
    int idx = blockIdx.x * 256 + threadIdx.x;  // flat over [B][CP][NN]
    int o = (idx / NN) & (CP - 1);
    const float invcnt = 1.f / (float)(BB * NN);
    float mean = bnred[o] * invcnt;
    float var = bnred[64 + o] * invcnt - mean * mean;
    float y = Y[idx];
    float zz = gamma[o] * (y - mean) * rsqrtf(var + 1e-5f) + beta[o];
    zz = fmaxf(zz, 0.f);
    out[idx] = pfeat[idx] + zz;
}

extern "C" void kernel_launch(void* const* d_in, const int* in_sizes, int n_in,
                              void* d_out, int out_size, void* d_ws, size_t ws_size,
                              hipStream_t stream) {
    const float* pts_img = (const float*)d_in[0];
    const float* img     = (const float*)d_in[1];
    const float* pfeat   = (const float*)d_in[2];
    const float* qkw     = (const float*)d_in[3];
    const float* vw      = (const float*)d_in[4];
    const float* vb      = (const float*)d_in[5];
    const float* tw      = (const float*)d_in[6];
    const float* tb      = (const float*)d_in[7];
    const float* gamma   = (const float*)d_in[8];
    const float* beta    = (const float*)d_in[9];

    // workspace layout (bytes), total ~7.4 MB
    char* base = (char*)d_ws;
    bf16_t* Qb      = (bf16_t*)(base);                 // 1,048,576  [B][N][32] bf16 (scaled by sqrt(log2 e))
    bf16_t* XVb     = (bf16_t*)(base + 1048576);       // 2,097,152  [B][64][N] bf16
    bf16_t* twb     = (bf16_t*)(base + 3145728);       // 8,192      [64][64] bf16
    float*  rowsumG = (float*)(base + 3153920);        // 65,536     [B][N]
    float*  bn      = (float*)(base + 3219456);        // 512        [2][64]
    float*  Y       = (float*)(base + 3219968);        // 4,194,304  [B][64][N] f32

    hipMemsetAsync(rowsumG, 0, (size_t)(BB * NN + 128) * sizeof(float), stream);
    k_prep<<<16, 256, 0, stream>>>(tw, twb);
    k_fuse<<<(BB * NN) / 4, 256, 0, stream>>>(pts_img, img, pfeat, qkw, vw, vb, Qb, XVb);
    k_rowsum<<<dim3(NN / 64, SPLITM, BB), 256, 0, stream>>>(Qb, rowsumG);
    k_attn<<<dim3(NN / 32, BB), 256, 0, stream>>>(Qb, XVb, rowsumG, pfeat, twb, tb, Y, bn);
    k_final<<<(BB * CP * NN) / 256, 256, 0, stream>>>(Y, pfeat, gamma, beta, bn, (float*)d_out);
}